// Round 2
// baseline (244.640 us; speedup 1.0000x reference)
//
#include <hip/hip_runtime.h>
#include <math.h>

// Problem: ProcessFeatures_83296595738632
// sat: (96,4,64,16) f32, grd: (96,4,64,16) f32
// corr[bs,bg,i] = sum_{h,j,k} sat[bs,h,(i+j)%64,k] * grd[bg,h,j,15-k]   (c-axis reversed)
// orien[bs,bg]  = argmax_i corr  (first-max tie-break)
// dot[bs,bg]    = sum_{h,j,k} sat[bs,h,(j+orien)%64,k] * grd[bg,h,j,k] / ||sat[bs]||
// distance[bg,bs] = 2 - 2*dot[bs,bg]
// d_out (float32 flat): sat(393216) | grd(393216) | distance(9216) | orien(9216 as float)

#define BS   96
#define H    4
#define W    64
#define C    16
#define BG   96
#define NB   8            // bg per block
#define NTH  256

#define SAT_ELEMS (BS*H*W*C)          // 393216
#define OUT_DIST  (2*SAT_ELEMS)       // 786432
#define OUT_ORIEN (OUT_DIST + BS*BG)  // 795648

// satL: linear 16-float rows, float4-chunk slot swizzle -> conflict-free b128:
//   chunk c4 of row hw stored at slot (c4 + (hw>>1)) & 3
__device__ __forceinline__ int satIdx(int hw, int c4) {
    return hw * 16 + 4 * ((c4 + (hw >> 1)) & 3);
}

__global__ __launch_bounds__(NTH, 4)
void pf_fused_kernel(const float* __restrict__ sat,
                     const float* __restrict__ grd,
                     float* __restrict__ out)
{
    __shared__ float satL[H * W * C];       // 16 KB, swizzled chunks
    __shared__ float partL[NB * 4 * W];     // 8 KB, [b][wv][lane] stride-4B
    __shared__ float sumL[4];
    __shared__ float dotP[NB * 4];
    __shared__ int   orienL[NB];

    const int bs   = blockIdx.y;
    const int bg0  = blockIdx.x * NB;
    const int tid  = threadIdx.x;
    const int wv   = tid >> 6;      // wave id == h slice
    const int lane = tid & 63;

    // ---- stage sat[bs] into swizzled LDS ----
    {
        const float4* satB = (const float4*)(sat + (size_t)bs * (H*W*C));
        for (int x = tid; x < H*W*C/4; x += NTH) {
            int hw = x >> 2;
            int c4 = x & 3;
            *(float4*)&satL[satIdx(hw, c4)] = satB[x];
        }
    }
    __syncthreads();

    // ---- per-h squared sums for the norm ----
    {
        float s = 0.f;
        const int hw = wv * W + lane;
        #pragma unroll
        for (int c4 = 0; c4 < 4; ++c4) {
            float4 v = *(const float4*)&satL[satIdx(hw, c4)];
            s += v.x*v.x + v.y*v.y + v.z*v.z + v.w*v.w;
        }
        #pragma unroll
        for (int off = 32; off; off >>= 1) s += __shfl_xor(s, off);
        if (lane == 0) sumL[wv] = s;
    }

    // ---- corr: lane = shift i, wave = h, 8 bg accumulators ----
    // grd addresses are wave-uniform -> force uniformity so they scalarize.
    const int hu = __builtin_amdgcn_readfirstlane(wv);
    const float* __restrict__ grdU = grd + ((size_t)(bg0 * H + hu) * W) * C;
    // per-b stride = H*W*C = 4096 floats; per-j stride = 16 floats

    float acc[NB];
    #pragma unroll
    for (int b = 0; b < NB; ++b) acc[b] = 0.f;

    #pragma unroll 4
    for (int j = 0; j < W; ++j) {
        const int rowBase = wv * W;
        const int r = (lane + j) & 63;
        float4 s4[4];
        #pragma unroll
        for (int c4 = 0; c4 < 4; ++c4)
            s4[c4] = *(const float4*)&satL[satIdx(rowBase + r, c4)];

        #pragma unroll
        for (int b = 0; b < NB; ++b) {
            const float* gRow = grdU + (size_t)b * (H*W*C) + j * C;
            #pragma unroll
            for (int c4 = 0; c4 < 4; ++c4) {
                // reversed-c pairing: sat[k0+t]*grd[15-(k0+t)]
                float4 g4 = *(const float4*)(gRow + (12 - 4*c4));
                acc[b] += s4[c4].x*g4.w + s4[c4].y*g4.z + s4[c4].z*g4.y + s4[c4].w*g4.x;
            }
        }
    }

    #pragma unroll
    for (int b = 0; b < NB; ++b) partL[(b*4 + wv) * W + lane] = acc[b];
    __syncthreads();

    // ---- argmax per bg (first-max tie-break, numpy semantics) ----
    for (int b = wv; b < NB; b += 4) {
        float v = (partL[(b*4+0)*W + lane] + partL[(b*4+1)*W + lane])
                + (partL[(b*4+2)*W + lane] + partL[(b*4+3)*W + lane]);
        int idx = lane;
        #pragma unroll
        for (int off = 32; off; off >>= 1) {
            float ov = __shfl_xor(v, off);
            int   oi = __shfl_xor(idx, off);
            if (ov > v || (ov == v && oi < idx)) { v = ov; idx = oi; }
        }
        if (lane == 0) {
            orienL[b] = idx;
            out[OUT_ORIEN + bs*BG + (bg0 + b)] = (float)idx;
        }
    }
    __syncthreads();

    const float nrm = sqrtf(sumL[0] + sumL[1] + sumL[2] + sumL[3] + 1e-8f);

    // ---- dot phase: wave = h, lane = j ----
    {
        float dp[NB];
        #pragma unroll
        for (int b = 0; b < NB; ++b) {
            const int row = (lane + orienL[b]) & 63;
            const float* gRow = grd + ((size_t)((bg0+b)*H + wv) * W + lane) * C;
            float s = 0.f;
            #pragma unroll
            for (int c4 = 0; c4 < 4; ++c4) {
                float4 s4 = *(const float4*)&satL[satIdx(wv*W + row, c4)];
                float4 g4 = *(const float4*)(gRow + 4*c4);
                s += s4.x*g4.x + s4.y*g4.y + s4.z*g4.z + s4.w*g4.w;
            }
            dp[b] = s;
        }
        #pragma unroll
        for (int b = 0; b < NB; ++b) {
            float s = dp[b];
            #pragma unroll
            for (int off = 32; off; off >>= 1) s += __shfl_xor(s, off);
            if (lane == 0) dotP[b*4 + wv] = s;
        }
    }
    __syncthreads();

    if (tid < NB) {
        float d = ((dotP[tid*4+0] + dotP[tid*4+1]) + (dotP[tid*4+2] + dotP[tid*4+3])) / nrm;
        out[OUT_DIST + (size_t)(bg0 + tid)*BS + bs] = 2.f - 2.f*d;
    }
}

extern "C" void kernel_launch(void* const* d_in, const int* in_sizes, int n_in,
                              void* d_out, int out_size, void* d_ws, size_t ws_size,
                              hipStream_t stream) {
    const float* sat = (const float*)d_in[0];
    const float* grd = (const float*)d_in[1];
    float* out = (float*)d_out;

    hipMemcpyAsync(out,             sat, (size_t)SAT_ELEMS * sizeof(float),
                   hipMemcpyDeviceToDevice, stream);
    hipMemcpyAsync(out + SAT_ELEMS, grd, (size_t)SAT_ELEMS * sizeof(float),
                   hipMemcpyDeviceToDevice, stream);

    dim3 grid(BG / NB, BS);   // (12, 96)
    pf_fused_kernel<<<grid, NTH, 0, stream>>>(sat, grd, out);
}

// Round 3
// 155.271 us; speedup vs baseline: 1.5756x; 1.5756x over previous
//
#include <hip/hip_runtime.h>
#include <math.h>

// Problem: ProcessFeatures_83296595738632
// sat: (96,4,64,16) f32, grd: (96,4,64,16) f32
// corr[bs,bg,i] = sum_{h,j,k} sat[bs,h,(i+j)%64,k] * grd[bg,h,j,15-k]   (c-axis reversed)
// orien[bs,bg]  = argmax_i corr  (first-max tie-break)
// dot[bs,bg]    = sum_{h,j,k} sat[bs,h,(j+orien)%64,k] * grd[bg,h,j,k] / ||sat[bs]||
// distance[bg,bs] = 2 - 2*dot[bs,bg]
// d_out (f32 flat): sat(393216) | grd(393216) | distance(9216) | orien(9216 as float)
//
// R3 structure: sat row in VGPRs (lane i holds row i of h=wv), grd rows as
// wave-uniform SGPR data (s_load), corr via per-(bg,j) scalar dot + 1
// ds_bpermute rotate. Only per-(bg,j) LDS traffic = one b32 bpermute.

#define BS   96
#define H    4
#define W    64
#define C    16
#define BG   96
#define NB   8
#define NTH  256

#define SAT_ELEMS (BS*H*W*C)          // 393216
#define OUT_DIST  (2*SAT_ELEMS)       // 786432
#define OUT_ORIEN (OUT_DIST + BS*BG)  // 795648

// satL swizzle: chunk c4 of row hw stored at slot (c4 + (hw>>1)) & 3
__device__ __forceinline__ int satIdx(int hw, int c4) {
    return hw * 16 + 4 * ((c4 + (hw >> 1)) & 3);
}

__device__ __forceinline__ float rot_add(int baddr, float p) {
    return __int_as_float(__builtin_amdgcn_ds_bpermute(baddr, __float_as_int(p)));
}

// p = sum_k satreg[k] * g[15-k]  (reversed-c pairing), 4 independent chains
__device__ __forceinline__ float dot_rev(const float4 s0, const float4 s1,
                                         const float4 s2, const float4 s3,
                                         const float* __restrict__ g) {
    float p0 = fmaf(s0.x, g[15], fmaf(s0.y, g[14], fmaf(s0.z, g[13], s0.w * g[12])));
    float p1 = fmaf(s1.x, g[11], fmaf(s1.y, g[10], fmaf(s1.z, g[ 9], s1.w * g[ 8])));
    float p2 = fmaf(s2.x, g[ 7], fmaf(s2.y, g[ 6], fmaf(s2.z, g[ 5], s2.w * g[ 4])));
    float p3 = fmaf(s3.x, g[ 3], fmaf(s3.y, g[ 2], fmaf(s3.z, g[ 1], s3.w * g[ 0])));
    return (p0 + p1) + (p2 + p3);
}

__global__ __launch_bounds__(NTH)
void pf_fused_kernel(const float* __restrict__ sat,
                     const float* __restrict__ grd,
                     float* __restrict__ out)
{
    __shared__ float satL[H * W * C];     // 16 KB (for dot phase)
    __shared__ float partL[NB * 4 * W];   // 8 KB
    __shared__ float sumL[4];
    __shared__ float dotP[NB * 4];
    __shared__ int   orienL[NB];

    const int bs   = blockIdx.y;
    const int bg0  = blockIdx.x * NB;
    const int tid  = threadIdx.x;
    const int wv   = tid >> 6;
    const int lane = tid & 63;

    // ---- sat row -> registers (coalesced: lane-consecutive 64B rows) ----
    const float4* sp = (const float4*)(sat + (((size_t)bs * H + wv) * W + lane) * C);
    const float4 s0 = sp[0], s1 = sp[1], s2 = sp[2], s3 = sp[3];

    // ---- stage satL for the dot phase (swizzled) ----
    {
        const int hw = wv * W + lane;
        *(float4*)&satL[satIdx(hw, 0)] = s0;
        *(float4*)&satL[satIdx(hw, 1)] = s1;
        *(float4*)&satL[satIdx(hw, 2)] = s2;
        *(float4*)&satL[satIdx(hw, 3)] = s3;
    }

    // ---- per-h squared sum for the norm ----
    {
        float a = fmaf(s0.x, s0.x, fmaf(s0.y, s0.y, fmaf(s0.z, s0.z, s0.w * s0.w)));
        float b = fmaf(s1.x, s1.x, fmaf(s1.y, s1.y, fmaf(s1.z, s1.z, s1.w * s1.w)));
        float c = fmaf(s2.x, s2.x, fmaf(s2.y, s2.y, fmaf(s2.z, s2.z, s2.w * s2.w)));
        float d = fmaf(s3.x, s3.x, fmaf(s3.y, s3.y, fmaf(s3.z, s3.z, s3.w * s3.w)));
        float s = (a + b) + (c + d);
        #pragma unroll
        for (int off = 32; off; off >>= 1) s += __shfl_xor(s, off);
        if (lane == 0) sumL[wv] = s;
    }

    // ---- corr phase: grd rows via scalar loads, rotate partials by bpermute ----
    // uniform base offset (floats) for this wave's h-slice of bg0's grd
    const int gbase = __builtin_amdgcn_readfirstlane((bg0 * H + wv) * W * C);

    #pragma unroll
    for (int bp = 0; bp < NB / 2; ++bp) {
        const float* __restrict__ gA = grd + gbase + (2 * bp    ) * (H * W * C);
        const float* __restrict__ gB = grd + gbase + (2 * bp + 1) * (H * W * C);
        float accA = 0.f, accB = 0.f;
        int baddr = lane << 2;              // bpermute byte addr of lane (lane+j)&63
        #pragma unroll 2
        for (int j = 0; j < W; ++j) {
            const float* rA = gA + j * C;
            const float* rB = gB + j * C;
            float pA = dot_rev(s0, s1, s2, s3, rA);
            float pB = dot_rev(s0, s1, s2, s3, rB);
            accA += rot_add(baddr, pA);
            accB += rot_add(baddr, pB);
            baddr = (baddr + 4) & 255;
        }
        partL[((2 * bp    ) * 4 + wv) * W + lane] = accA;
        partL[((2 * bp + 1) * 4 + wv) * W + lane] = accB;
    }
    __syncthreads();

    // ---- argmax per bg (first-max tie-break, numpy semantics) ----
    for (int b = wv; b < NB; b += 4) {
        float v = (partL[(b*4+0)*W + lane] + partL[(b*4+1)*W + lane])
                + (partL[(b*4+2)*W + lane] + partL[(b*4+3)*W + lane]);
        int idx = lane;
        #pragma unroll
        for (int off = 32; off; off >>= 1) {
            float ov = __shfl_xor(v, off);
            int   oi = __shfl_xor(idx, off);
            if (ov > v || (ov == v && oi < idx)) { v = ov; idx = oi; }
        }
        if (lane == 0) {
            orienL[b] = idx;
            out[OUT_ORIEN + bs*BG + (bg0 + b)] = (float)idx;
        }
    }
    __syncthreads();

    const float nrm = sqrtf(sumL[0] + sumL[1] + sumL[2] + sumL[3] + 1e-8f);

    // ---- dot phase: wave = h, lane = j; sat from satL, grd coalesced global ----
    {
        float dp[NB];
        #pragma unroll
        for (int b = 0; b < NB; ++b) {
            const int row = (lane + orienL[b]) & 63;
            const float* gRow = grd + (((size_t)(bg0 + b) * H + wv) * W + lane) * C;
            float s = 0.f;
            #pragma unroll
            for (int c4 = 0; c4 < 4; ++c4) {
                float4 sv = *(const float4*)&satL[satIdx(wv * W + row, c4)];
                float4 gv = *(const float4*)(gRow + 4 * c4);
                s += sv.x*gv.x + sv.y*gv.y + sv.z*gv.z + sv.w*gv.w;
            }
            dp[b] = s;
        }
        #pragma unroll
        for (int b = 0; b < NB; ++b) {
            float s = dp[b];
            #pragma unroll
            for (int off = 32; off; off >>= 1) s += __shfl_xor(s, off);
            if (lane == 0) dotP[b*4 + wv] = s;
        }
    }
    __syncthreads();

    if (tid < NB) {
        float d = ((dotP[tid*4+0] + dotP[tid*4+1]) + (dotP[tid*4+2] + dotP[tid*4+3])) / nrm;
        out[OUT_DIST + (size_t)(bg0 + tid)*BS + bs] = 2.f - 2.f*d;
    }
}

extern "C" void kernel_launch(void* const* d_in, const int* in_sizes, int n_in,
                              void* d_out, int out_size, void* d_ws, size_t ws_size,
                              hipStream_t stream) {
    const float* sat = (const float*)d_in[0];
    const float* grd = (const float*)d_in[1];
    float* out = (float*)d_out;

    hipMemcpyAsync(out,             sat, (size_t)SAT_ELEMS * sizeof(float),
                   hipMemcpyDeviceToDevice, stream);
    hipMemcpyAsync(out + SAT_ELEMS, grd, (size_t)SAT_ELEMS * sizeof(float),
                   hipMemcpyDeviceToDevice, stream);

    dim3 grid(BG / NB, BS);   // (12, 96)
    pf_fused_kernel<<<grid, NTH, 0, stream>>>(sat, grd, out);
}